// Round 17
// baseline (196.748 us; speedup 1.0000x reference)
//
#include <hip/hip_runtime.h>
#include <stdint.h>

typedef int v4i __attribute__((ext_vector_type(4)));
typedef int v16i __attribute__((ext_vector_type(16)));

#define K_DIM 4096
#define TPB_Q 256
#define BM 256
#define BN 256
#define BKB 128                     // K-bytes per tile
#define NT (K_DIM / BKB)            // 32 K-tiles
#define TILE_BYTES (256 * BKB)      // 32 KiB per operand tile

__device__ __forceinline__ void load_lds16(const void* g, void* l) {
  __builtin_amdgcn_global_load_lds(
      (const __attribute__((address_space(1))) void*)g,
      (__attribute__((address_space(3))) void*)l, 16, 0, 0);
}

// ---------------- per-row symmetric int8 quant (BW-bound, unchanged) --------
__global__ __launch_bounds__(TPB_Q) void quant_rows_kernel(
    const float* __restrict__ x, signed char* __restrict__ q,
    float* __restrict__ scales) {
  const int row = blockIdx.x;
  const float4* xr = (const float4*)(x + (size_t)row * K_DIM);
  float4 v[4];
  float m = 0.0f;
#pragma unroll
  for (int i = 0; i < 4; ++i) {
    v[i] = xr[threadIdx.x + i * TPB_Q];
    m = fmaxf(m, fmaxf(fmaxf(fabsf(v[i].x), fabsf(v[i].y)),
                       fmaxf(fabsf(v[i].z), fabsf(v[i].w))));
  }
#pragma unroll
  for (int off = 32; off > 0; off >>= 1) m = fmaxf(m, __shfl_down(m, off));
  __shared__ float red[TPB_Q / 64];
  if ((threadIdx.x & 63) == 0) red[threadIdx.x >> 6] = m;
  __syncthreads();
  m = fmaxf(fmaxf(red[0], red[1]), fmaxf(red[2], red[3]));
  const float scale = fmaxf(m / 127.0f, 1e-8f);
  if (threadIdx.x == 0) scales[row] = scale;
  uint32_t* qr = (uint32_t*)(q + (size_t)row * K_DIM);
#pragma unroll
  for (int i = 0; i < 4; ++i) {
    const float4 t = v[i];
    const int a0 = (int)fminf(fmaxf(rintf(t.x / scale), -128.0f), 127.0f);
    const int a1 = (int)fminf(fmaxf(rintf(t.y / scale), -128.0f), 127.0f);
    const int a2 = (int)fminf(fmaxf(rintf(t.z / scale), -128.0f), 127.0f);
    const int a3 = (int)fminf(fmaxf(rintf(t.w / scale), -128.0f), 127.0f);
    const uint32_t p = (uint32_t)(a0 & 255) | ((uint32_t)(a1 & 255) << 8) |
                       ((uint32_t)(a2 & 255) << 16) | ((uint32_t)(a3 & 255) << 24);
    qr[threadIdx.x + i * TPB_Q] = p;
  }
}

// ---- 256x256 i8 GEMM, 32x32x32 MFMA, ks-grouped fine interleave -----------
// 8 waves (wm 2 x wn 4); per-wave C 128x64 = acc[4][2] of i32x16 (128 AGPR).
// Fragments a[4][4]+b[2][4] = 96 VGPR. 32x32x32 layouts (R15-verified):
// A/B row/col = lane&31, k = (lane>>5)*16+elem; C/D col = lane&31,
// row = (r&3)+8*(r>>2)+4*(lane>>5).
// R16 change vs R15: reads grouped BY K-SLICE (6 each: b01+a0123 of one ks)
// with R8-style fine gates -- issue g0,g1; stage(T+1); lgkm(6)->MFMA ks0;
// issue g2; lgkm(6)->ks1; issue g3; lgkm(6)->ks2; lgkm(0)->ks3. Tests the
// hypothesis that R15's 1.26e7 bank conflicts came from the coarse 16-read
// burst overlapping staging writes, not from the read pattern itself.
// LDS: A,B full-tile dbuf (128 KiB), 16B-chunk XOR swizzle phys = logical ^
// (row&7); stage dest linear, source inverse-swizzled.
// XCD swizzle: grid 32r x 16c; XCD k owns rows[8*(k>>1),+8) x cols[8*(k&1),+8).
__global__ __launch_bounds__(512, 2) void gemm_i8_kernel(
    const signed char* __restrict__ qA, const signed char* __restrict__ qB,
    const float* __restrict__ sA, const float* __restrict__ sB,
    float* __restrict__ C, int M, int N, int K) {
  __shared__ __align__(16) signed char As[2 * TILE_BYTES];  // 64 KiB
  __shared__ __align__(16) signed char Bs[2 * TILE_BYTES];  // 64 KiB

  const int tid = threadIdx.x;
  const int wave = tid >> 6, lane = tid & 63;
  const int l32 = lane & 31, l5 = lane >> 5;
  const int wm = wave >> 2, wn = wave & 3;

  // XCD-chunked 2-D swizzle (bijective; 512 blocks, 8 XCDs, o%8 = XCD)
  const int o = blockIdx.x + blockIdx.y * gridDim.x;
  const int xcd = o & 7, slot = o >> 3;
  const int rb = ((xcd >> 1) << 3) + (slot >> 3);  // grid row 0..31
  const int cb = ((xcd & 1) << 3) + (slot & 7);    // grid col 0..15
  const int m0 = rb * BM, n0 = cb * BN;

  const signed char* Abase = qA + (size_t)m0 * K;
  const signed char* Bbase = qB + (size_t)n0 * K;

  // staging: tile = 2048 x 16B chunks; thread d = s*512+tid, s=0..3.
  // dest linear (wave-uniform base + lane*16); source inverse-swizzled.
  int soff[4], sdst[4];
#pragma unroll
  for (int s = 0; s < 4; ++s) {
    const int d = s * 512 + tid;
    const int r = d >> 3;
    const int c = (d & 7) ^ (r & 7);
    soff[s] = r * K + c * 16;
    sdst[s] = s * 8192 + wave * 1024;
  }

#define STAGE_A(T_)                                                         \
  do {                                                                      \
    _Pragma("unroll") for (int s = 0; s < 4; ++s)                           \
        load_lds16(Abase + (size_t)(T_)*BKB + soff[s],                      \
                   As + ((T_)&1) * TILE_BYTES + sdst[s]);                   \
  } while (0)
#define STAGE_B(T_)                                                         \
  do {                                                                      \
    _Pragma("unroll") for (int s = 0; s < 4; ++s)                           \
        load_lds16(Bbase + (size_t)(T_)*BKB + soff[s],                      \
                   Bs + ((T_)&1) * TILE_BYTES + sdst[s]);                   \
  } while (0)

  // fragment ds_read offsets: logical chunk = ks*2 + l5, row&7 = l32&7
  int axor[4];
#pragma unroll
  for (int ks = 0; ks < 4; ++ks)
    axor[ks] = (((ks * 2 + l5) ^ (l32 & 7)) << 4);
  const int aoff = wm * 16384 + l32 * 128;  // + mi*4096 (32 rows)
  const int boff = wn * 8192 + l32 * 128;   // + nj*4096

  const v16i vz16 = {0, 0, 0, 0, 0, 0, 0, 0, 0, 0, 0, 0, 0, 0, 0, 0};
  v16i acc[4][2];
#pragma unroll
  for (int i = 0; i < 4; ++i)
#pragma unroll
    for (int j = 0; j < 2; ++j) acc[i][j] = vz16;

  // prologue: stage tile 0, drain, sync.
  STAGE_A(0); STAGE_B(0);
  asm volatile("s_waitcnt vmcnt(0)" ::: "memory");
  __builtin_amdgcn_s_barrier();

// 6 reads of one k-slice: b[0..1][ks], a[0..3][ks]
#define READ_G(ks_)                                                          \
  do {                                                                       \
    b[0][ks_] = *(const v4i*)(Br + boff + 0 * 4096 + axor[ks_]);             \
    b[1][ks_] = *(const v4i*)(Br + boff + 1 * 4096 + axor[ks_]);             \
    _Pragma("unroll") for (int mi = 0; mi < 4; ++mi)                         \
        a[mi][ks_] = *(const v4i*)(Ar + aoff + mi * 4096 + axor[ks_]);       \
    __builtin_amdgcn_sched_barrier(0);                                       \
  } while (0)

// 8 MFMA of one k-slice (4mi x 2nj, all acc distinct)
#define MFMA_KS(ks_)                                                         \
  do {                                                                       \
    __builtin_amdgcn_s_setprio(1);                                           \
    _Pragma("unroll") for (int mi = 0; mi < 4; ++mi) {                       \
      acc[mi][0] = __builtin_amdgcn_mfma_i32_32x32x32_i8(                    \
          a[mi][ks_], b[0][ks_], acc[mi][0], 0, 0, 0);                       \
      acc[mi][1] = __builtin_amdgcn_mfma_i32_32x32x32_i8(                    \
          a[mi][ks_], b[1][ks_], acc[mi][1], 0, 0, 0);                       \
    }                                                                        \
    __builtin_amdgcn_s_setprio(0);                                           \
  } while (0)

#define LGKM_GATE(n_)                                       \
  do {                                                      \
    asm volatile("s_waitcnt lgkmcnt(" #n_ ")" ::: "memory");\
    __builtin_amdgcn_sched_barrier(0);                      \
  } while (0)

  for (int T = 0; T < NT; ++T) {
    const signed char* Ar = As + (T & 1) * TILE_BYTES;
    const signed char* Br = Bs + (T & 1) * TILE_BYTES;
    v4i a[4][4], b[2][4];

    // issue ks0, ks1 read groups (12 reads in flight)
    READ_G(0);
    READ_G(1);

    // stage next tile into buf^1 (no WAR: reads are from buf; vmcnt only)
    if (T + 1 < NT) { STAGE_A(T + 1); STAGE_B(T + 1); }

    LGKM_GATE(6);   // g0 done (g1 still in flight)
    MFMA_KS(0);
    READ_G(2);      // issue ks2 under cover of ks1's data wait
    LGKM_GATE(6);   // g1 done (g2 in flight)
    MFMA_KS(1);
    READ_G(3);      // issue ks3
    LGKM_GATE(6);   // g2 done (g3 in flight)
    MFMA_KS(2);
    LGKM_GATE(0);   // g3 done
    MFMA_KS(3);

    // boundary: own stage landed (covered by MFMA span), cross-wave fence
    asm volatile("s_waitcnt vmcnt(0)" ::: "memory");
    __builtin_amdgcn_s_barrier();
  }

  // epilogue: 32x32 C/D layout: col = lane&31, row = (r&3)+8*(r>>2)+4*(lane>>5)
  float sbv[2];
#pragma unroll
  for (int nj = 0; nj < 2; ++nj) sbv[nj] = sB[n0 + wn * 64 + nj * 32 + l32];
#pragma unroll
  for (int mi = 0; mi < 4; ++mi) {
#pragma unroll
    for (int r = 0; r < 16; ++r) {
      const int row = m0 + wm * 128 + mi * 32 + (r & 3) + 8 * (r >> 2) + 4 * l5;
      const float sav = sA[row];
      float* crow = C + (size_t)row * N + (n0 + wn * 64 + l32);
#pragma unroll
      for (int nj = 0; nj < 2; ++nj)
        crow[nj * 32] = (float)acc[mi][nj][r] * sav * sbv[nj];
    }
  }
}

extern "C" void kernel_launch(void* const* d_in, const int* in_sizes, int n_in,
                              void* d_out, int out_size, void* d_ws, size_t ws_size,
                              hipStream_t stream) {
  const float* A = (const float*)d_in[0];
  const float* B = (const float*)d_in[1];
  float* C = (float*)d_out;
  const int K = K_DIM;
  const int M = in_sizes[0] / K;  // 8192
  const int N = in_sizes[1] / K;  // 4096

  signed char* qA = (signed char*)d_ws;
  signed char* qB = qA + (size_t)M * K;
  float* sA = (float*)(qB + (size_t)N * K);
  float* sB = sA + M;

  quant_rows_kernel<<<M, TPB_Q, 0, stream>>>(A, qA, sA);
  quant_rows_kernel<<<N, TPB_Q, 0, stream>>>(B, qB, sB);

  dim3 grid(N / BN, M / BM);
  gemm_i8_kernel<<<grid, 512, 0, stream>>>(qA, qB, sA, sB, C, M, N, K);
}